// Round 4
// baseline (446.230 us; speedup 1.0000x reference)
//
#include <hip/hip_runtime.h>
#include <hip/hip_bf16.h>
#include <math.h>

// ---------------------------------------------------------------------------
// PatentCitationMoEModule — MI355X implementation, round 4
//  - expert_gemm rebuilt: 64x64 tiles (4 blocks/CU), swizzled k-major LDS
//    staging (conflict-free ds_read_b128 at lane*16), double-buffered LDS
//    (1 barrier / K-iter).
//  - 3 weight transposes merged into one dispatch.
//  - all other kernels identical to round 3 (passing, absmax 0.031).
// ---------------------------------------------------------------------------

#define LN_EPS 1e-5f

typedef __bf16 bf16_t;
typedef __bf16 bf16x8 __attribute__((ext_vector_type(8)));
typedef __bf16 bf16x4 __attribute__((ext_vector_type(4)));
typedef float f32x4 __attribute__((ext_vector_type(4)));

__device__ __forceinline__ void async_ld16(const void* g, void* l) {
  __builtin_amdgcn_global_load_lds(
      (__attribute__((address_space(1))) void*)g,
      (__attribute__((address_space(3))) void*)l, 16, 0, 0);
}

// --------------------------- prep: kq vector -------------------------------
__global__ __launch_bounds__(256)
void prep_kq(const float* __restrict__ Wq, const float* __restrict__ bq,
             const float* __restrict__ Wk, const float* __restrict__ bk,
             const float* __restrict__ gc, float* __restrict__ kq_out) {
  __shared__ float q[256];
  __shared__ float red[4];
  const int t = threadIdx.x, bi = blockIdx.x;
  float s = bq[t];
  for (int d = 0; d < 256; d++) s += gc[d] * Wq[d * 256 + t];
  q[t] = s;
  __syncthreads();
  const int rl = t >> 5, sl = t & 31;
  const int r = bi * 8 + rl;
  float p = 0.f;
#pragma unroll
  for (int i = 0; i < 8; i++) { const int d = sl + 32 * i; p += Wk[r * 256 + d] * q[d]; }
#pragma unroll
  for (int o = 16; o > 0; o >>= 1) p += __shfl_down(p, o, 32);
  if (sl == 0) kq_out[r] = p;
  if (bi == 0) {
    float z = q[t] * bk[t];
    const int lane = t & 63, wave = t >> 6;
#pragma unroll
    for (int o = 32; o > 0; o >>= 1) z += __shfl_down(z, o);
    if (lane == 0) red[wave] = z;
    __syncthreads();
    if (t == 0) kq_out[256] = red[0] + red[1] + red[2] + red[3];
  }
}

// ---------------- merged weight transpose + fp32->bf16 ---------------------
// z in [0,8): W1 [512,1024]; [8,16): W2 [1024,1024]; [16,24): W3 [1024,512].
// W [E][R][C] fp32 -> Wt [E][C][R] bf16, 64x64 tiles.
__global__ __launch_bounds__(256)
void transpose_all(const float* __restrict__ W1, const float* __restrict__ W2,
                   const float* __restrict__ W3, bf16_t* __restrict__ W1t,
                   bf16_t* __restrict__ W2t, bf16_t* __restrict__ W3t) {
  __shared__ float tile[64][65];
  const int z = blockIdx.z;
  const float* W; bf16_t* Wt; int R, C, e;
  if (z < 8)       { W = W1; Wt = W1t; R = 512;  C = 1024; e = z; }
  else if (z < 16) { W = W2; Wt = W2t; R = 1024; C = 1024; e = z - 8; }
  else             { W = W3; Wt = W3t; R = 1024; C = 512;  e = z - 16; }
  const int c0 = blockIdx.x * 64, r0 = blockIdx.y * 64;
  if (c0 >= C || r0 >= R) return;
  const int tq = threadIdx.x & 15, th = threadIdx.x >> 4;  // 16 x 16
  const float* Wp = W + (size_t)e * R * C;
  bf16_t* Wtp = Wt + (size_t)e * R * C;
#pragma unroll
  for (int i = 0; i < 4; i++) {
    const int row = th + 16 * i;
    *(float4*)&tile[row][tq * 4] = *(const float4*)(Wp + (size_t)(r0 + row) * C + c0 + tq * 4);
  }
  __syncthreads();
#pragma unroll
  for (int i = 0; i < 4; i++) {
    const int c_loc = th + 16 * i;
    bf16x4 o;
#pragma unroll
    for (int j = 0; j < 4; j++) o[j] = (bf16_t)tile[tq * 4 + j][c_loc];
    *(bf16x4*)(Wtp + (size_t)(c0 + c_loc) * R + r0 + tq * 4) = o;
  }
}

// ---------------- dense score table: tab[v] = emb[v] . kq -------------------
__global__ __launch_bounds__(256)
void score_tab_kernel(const float* __restrict__ ipc_emb,
                      const float* __restrict__ role_emb,
                      const float* __restrict__ kq_qbk, float* __restrict__ tab) {
  const int wave = threadIdx.x >> 6, lane = threadIdx.x & 63;
  const float4 kq = *(const float4*)(kq_qbk + lane * 4);
  const int base = (blockIdx.x * 4 + wave) * 32;
  for (int i = 0; i < 32; i++) {
    const int r = base + i;
    if (r >= 50016) return;
    const float* src = (r < 50000) ? (ipc_emb + (size_t)r * 256)
                                   : (role_emb + (size_t)(r - 50000) * 256);
    const float4 v = *(const float4*)(src + lane * 4);
    float p = v.x * kq.x + v.y * kq.y + v.z * kq.z + v.w * kq.w;
#pragma unroll
    for (int o = 32; o > 0; o >>= 1) p += __shfl_down(p, o);
    if (lane == 0) tab[r] = (r < 50000) ? p : (p + kq_qbk[256]);
  }
}

// -------------------- xbar: softmax + single-pass gather --------------------
__global__ __launch_bounds__(256)
void xbar_kernel(const int* __restrict__ ipc_idx, const int* __restrict__ role_idx,
                 const int* __restrict__ maskp,
                 const float* __restrict__ ipc_emb, const float* __restrict__ role_emb,
                 const float* __restrict__ tab, float* __restrict__ xbar_g) {
  const int b = blockIdx.x;
  __shared__ float attn_s[64];
  __shared__ __align__(16) float part[4][256];
  const int t = threadIdx.x, wave = t >> 6, lane = t & 63;
  const int d0 = lane * 4;
  if (wave == 0) {
    const int ii = ipc_idx[b * 64 + lane], ri = role_idx[b * 64 + lane];
    float s = tab[ii] + tab[50000 + ri];
    s = (maskp[b * 64 + lane] == 0) ? -1e9f : s;
    float m = s;
#pragma unroll
    for (int o = 32; o > 0; o >>= 1) m = fmaxf(m, __shfl_xor(m, o));
    const float ev = expf(s - m);
    float sum = ev;
#pragma unroll
    for (int o = 32; o > 0; o >>= 1) sum += __shfl_xor(sum, o);
    attn_s[lane] = ev / sum;
  }
  __syncthreads();
  float p0 = 0.f, p1 = 0.f, p2 = 0.f, p3 = 0.f;
  for (int l = wave; l < 64; l += 4) {
    const float a = attn_s[l];
    const int ii = ipc_idx[b * 64 + l], ri = role_idx[b * 64 + l];
    const float4 xe = *(const float4*)(ipc_emb + (size_t)ii * 256 + d0);
    const float4 re = *(const float4*)(role_emb + (size_t)ri * 256 + d0);
    p0 += a * (xe.x + re.x); p1 += a * (xe.y + re.y);
    p2 += a * (xe.z + re.z); p3 += a * (xe.w + re.w);
  }
  *(float4*)&part[wave][d0] = make_float4(p0, p1, p2, p3);
  __syncthreads();
  xbar_g[(size_t)b * 256 + t] = part[0][t] + part[1][t] + part[2][t] + part[3][t];
}

// ------------- pool: pooled = xbar@Wv + bv, LN, gate, top2 ------------------
__global__ __launch_bounds__(256)
void pool_kernel(const float* __restrict__ xbar_g, const float* __restrict__ Wv,
                 const float* __restrict__ bvec,
                 const float* __restrict__ ln_g, const float* __restrict__ ln_b,
                 const float* __restrict__ gate_W, const float* __restrict__ gate_b,
                 const float* __restrict__ expert_biases,
                 float* __restrict__ out_idx_f, int* __restrict__ ws_idx,
                 float* __restrict__ ws_gw) {
  const int rb = blockIdx.x * 8;
  __shared__ __align__(16) float xs[8][256];
  __shared__ __align__(16) float ps[8][260];
  const int t = threadIdx.x, wave = t >> 6, lane = t & 63;
  for (int i = t; i < 512; i += 256)
    ((float4*)xs)[i] = ((const float4*)(xbar_g + (size_t)rb * 256))[i];
  __syncthreads();
  const float* x0 = xs[wave * 2];
  const float* x1 = xs[wave * 2 + 1];
  f32x4 acc0 = {0.f, 0.f, 0.f, 0.f}, acc1 = {0.f, 0.f, 0.f, 0.f};
  for (int d = 0; d < 256; d += 4) {
    const float4 xa = *(const float4*)(x0 + d);
    const float4 xb = *(const float4*)(x1 + d);
#pragma unroll
    for (int j = 0; j < 4; j++) {
      const float4 wv = *(const float4*)(Wv + (size_t)(d + j) * 256 + lane * 4);
      const float aj = (&xa.x)[j], bj = (&xb.x)[j];
      acc0.x += aj * wv.x; acc0.y += aj * wv.y; acc0.z += aj * wv.z; acc0.w += aj * wv.w;
      acc1.x += bj * wv.x; acc1.y += bj * wv.y; acc1.z += bj * wv.z; acc1.w += bj * wv.w;
    }
  }
  const float4 bvv = *(const float4*)(bvec + lane * 4);
  acc0.x += bvv.x; acc0.y += bvv.y; acc0.z += bvv.z; acc0.w += bvv.w;
  acc1.x += bvv.x; acc1.y += bvv.y; acc1.z += bvv.z; acc1.w += bvv.w;
  *(f32x4*)&ps[wave * 2][lane * 4] = acc0;
  *(f32x4*)&ps[wave * 2 + 1][lane * 4] = acc1;
  __syncthreads();
  const float4 lg = *(const float4*)(ln_g + lane * 4);
  const float4 lb = *(const float4*)(ln_b + lane * 4);
#pragma unroll
  for (int rr = 0; rr < 2; rr++) {
    const int r = wave * 2 + rr;
    const float4 v = *(const float4*)&ps[r][lane * 4];
    float s1 = v.x + v.y + v.z + v.w;
#pragma unroll
    for (int o = 32; o > 0; o >>= 1) s1 += __shfl_xor(s1, o);
    const float mu = s1 * (1.f / 256.f);
    const float4 df = make_float4(v.x - mu, v.y - mu, v.z - mu, v.w - mu);
    float s2 = df.x * df.x + df.y * df.y + df.z * df.z + df.w * df.w;
#pragma unroll
    for (int o = 32; o > 0; o >>= 1) s2 += __shfl_xor(s2, o);
    const float inv = 1.f / sqrtf(s2 * (1.f / 256.f) + LN_EPS);
    f32x4 rv;
    rv[0] = df.x * inv * lg.x + lb.x; rv[1] = df.y * inv * lg.y + lb.y;
    rv[2] = df.z * inv * lg.z + lb.z; rv[3] = df.w * inv * lg.w + lb.w;
    f32x4 pa = {0.f, 0.f, 0.f, 0.f}, pb = {0.f, 0.f, 0.f, 0.f};
#pragma unroll
    for (int k = 0; k < 4; k++) {
      const int d = lane * 4 + k;
      const f32x4 g0 = *(const f32x4*)(gate_W + d * 8);
      const f32x4 g1 = *(const f32x4*)(gate_W + d * 8 + 4);
      pa += rv[k] * g0;
      pb += rv[k] * g1;
    }
#pragma unroll
    for (int o = 32; o > 0; o >>= 1) {
      pa[0] += __shfl_down(pa[0], o); pa[1] += __shfl_down(pa[1], o);
      pa[2] += __shfl_down(pa[2], o); pa[3] += __shfl_down(pa[3], o);
      pb[0] += __shfl_down(pb[0], o); pb[1] += __shfl_down(pb[1], o);
      pb[2] += __shfl_down(pb[2], o); pb[3] += __shfl_down(pb[3], o);
    }
    if (lane == 0) {
      float aff[8];
#pragma unroll
      for (int j = 0; j < 4; j++) { aff[j] = pa[j] + gate_b[j]; aff[4 + j] = pb[j] + gate_b[4 + j]; }
      float b0 = -1e30f; int i0 = 0;
#pragma unroll
      for (int j = 0; j < 8; j++) {
        const float s = aff[j] + expert_biases[j];
        if (s > b0) { b0 = s; i0 = j; }
      }
      float b1v = -1e30f; int i1 = 0;
#pragma unroll
      for (int j = 0; j < 8; j++) {
        const float s = aff[j] + expert_biases[j];
        if (j != i0 && s > b1v) { b1v = s; i1 = j; }
      }
      const float a0 = aff[i0], a1 = aff[i1];
      const float m = fmaxf(a0, a1);
      const float e0 = expf(a0 - m), e1 = expf(a1 - m);
      const float invs = 1.f / (e0 + e1);
      const int bg = rb + r;
      ws_idx[bg * 2] = i0; ws_idx[bg * 2 + 1] = i1;
      ws_gw[bg * 2] = e0 * invs; ws_gw[bg * 2 + 1] = e1 * invs;
      out_idx_f[bg * 2] = (float)i0; out_idx_f[bg * 2 + 1] = (float)i1;
    }
  }
}

// ------------------------------ pack ---------------------------------------
__global__ __launch_bounds__(256)
void pack_kernel(const int* __restrict__ ws_idx, int* __restrict__ list_token,
                 int* __restrict__ a_of, int* __restrict__ offsets_g) {
  __shared__ int cnt[8]; __shared__ int off[9]; __shared__ int fill[8];
  const int t = threadIdx.x;
  if (t < 8) cnt[t] = 0;
  __syncthreads();
  for (int a = t; a < 4096; a += 256) atomicAdd(&cnt[ws_idx[a]], 1);
  __syncthreads();
  if (t == 0) { off[0] = 0; for (int e = 0; e < 8; e++) off[e + 1] = off[e] + cnt[e]; }
  __syncthreads();
  if (t < 8) fill[t] = off[t];
  if (t < 9) offsets_g[t] = off[t];
  __syncthreads();
  for (int a = t; a < 4096; a += 256) {
    const int e = ws_idx[a];
    const int pos = atomicAdd(&fill[e], 1);
    list_token[pos] = a >> 1;
    a_of[a] = pos;
  }
}

// --------------------------- gather bib -> bf16 ----------------------------
__global__ __launch_bounds__(64)
void gather_bib(const float* __restrict__ bib, const int* __restrict__ list_token,
                bf16_t* __restrict__ Xc) {
  const int a = blockIdx.x;
  const int tok = list_token[a];
  const int t = threadIdx.x;
  const float4 v1 = *(const float4*)(bib + (size_t)tok * 512 + t * 8);
  const float4 v2 = *(const float4*)(bib + (size_t)tok * 512 + t * 8 + 4);
  bf16x8 o;
  o[0] = (bf16_t)v1.x; o[1] = (bf16_t)v1.y; o[2] = (bf16_t)v1.z; o[3] = (bf16_t)v1.w;
  o[4] = (bf16_t)v2.x; o[5] = (bf16_t)v2.y; o[6] = (bf16_t)v2.z; o[7] = (bf16_t)v2.w;
  *(bf16x8*)(Xc + (size_t)a * 512 + t * 8) = o;
}

// --------------------- expert GEMM, round-4 structure -----------------------
// C[rows, Nt] = A[rows, K] @ B; Bt = B^T [E][Nt][K]; rows segmented by expert.
// 64x64 tile, BK=32, double-buffered LDS, swizzled k-major staging:
//   chunk c (16 rows) staged so LDS slot lane*16B holds
//   [row = c*16 + (lane&15)][k = (lane>>4)*8 .. +7]  == MFMA A-frag order.
// Frag read = ds_read_b128 at lane*16 — conflict-free, no address math.
template <bool RELU, typename OUT_T>
__global__ __launch_bounds__(256)
void expert_gemm(const bf16_t* __restrict__ A, const bf16_t* __restrict__ Bt,
                 const float* __restrict__ bias, OUT_T* __restrict__ C,
                 const int* __restrict__ offsets, int K, int Nt) {
  const int e = blockIdx.z;
  const int seg_hi = offsets[e + 1];
  const int row0 = offsets[e] + blockIdx.y * 64;
  if (row0 >= seg_hi) return;
  const int n0 = blockIdx.x * 64;
  __shared__ __align__(16) bf16_t As[2 * 2048];  // 2 bufs x 4 chunks x 512
  __shared__ __align__(16) bf16_t Bs[2 * 2048];
  const int t = threadIdx.x, wave = t >> 6, lane = t & 63;
  const int wm = wave >> 1, wn = wave & 1;
  // per-lane global sources (swizzled): row = wave*16 + (lane&15), kgrp = lane>>4
  const bf16_t* Ag = A + (size_t)(row0 + wave * 16 + (lane & 15)) * K + (lane >> 4) * 8;
  const bf16_t* Bg = Bt + ((size_t)e * Nt + n0 + wave * 16 + (lane & 15)) * K + (lane >> 4) * 8;
  bf16_t* laW = As + wave * 512;  // wave-uniform LDS dst base
  bf16_t* lbW = Bs + wave * 512;
  f32x4 acc[2][2];
#pragma unroll
  for (int i = 0; i < 2; i++)
#pragma unroll
    for (int j = 0; j < 2; j++) acc[i][j] = (f32x4){0.f, 0.f, 0.f, 0.f};
  // prologue: stage k=0 into buf 0
  async_ld16(Ag, laW);
  async_ld16(Bg, lbW);
  int buf = 0;
  for (int kk = 32; kk <= K; kk += 32) {
    __syncthreads();  // buf staged (drains vmcnt), prev buf reads done
    if (kk < K) {
      async_ld16(Ag + kk, laW + (buf ^ 1) * 2048);
      async_ld16(Bg + kk, lbW + (buf ^ 1) * 2048);
    }
    bf16x8 af[2], bfv[2];
    const bf16_t* Ab = As + buf * 2048 + lane * 8;
    const bf16_t* Bb = Bs + buf * 2048 + lane * 8;
#pragma unroll
    for (int mi = 0; mi < 2; mi++) af[mi] = *(const bf16x8*)(Ab + (wm * 2 + mi) * 512);
#pragma unroll
    for (int ni = 0; ni < 2; ni++) bfv[ni] = *(const bf16x8*)(Bb + (wn * 2 + ni) * 512);
#pragma unroll
    for (int mi = 0; mi < 2; mi++)
#pragma unroll
      for (int ni = 0; ni < 2; ni++)
        acc[mi][ni] = __builtin_amdgcn_mfma_f32_16x16x32_bf16(af[mi], bfv[ni], acc[mi][ni], 0, 0, 0);
    buf ^= 1;
  }
  // epilogue: C/D layout row=(lane>>4)*4+r, col=lane&15  [m89/m91 verified]
  const int fr = lane & 15;
#pragma unroll
  for (int ni = 0; ni < 2; ni++) {
    const int col = n0 + wn * 32 + ni * 16 + fr;
    const float bv = bias[e * Nt + col];
#pragma unroll
    for (int mi = 0; mi < 2; mi++) {
#pragma unroll
      for (int r = 0; r < 4; r++) {
        const int grow = row0 + wm * 32 + mi * 16 + (lane >> 4) * 4 + r;
        if (grow < seg_hi) {
          float v = acc[mi][ni][r] + bv;
          if (RELU) v = fmaxf(v, 0.f);
          C[(size_t)grow * Nt + col] = (OUT_T)v;
        }
      }
    }
  }
}

// ------------------------------ head ---------------------------------------
__global__ __launch_bounds__(256)
void head_kernel(const float* __restrict__ O, const int* __restrict__ a_of,
                 const float* __restrict__ ws_gw, const float* __restrict__ head_W,
                 const float* __restrict__ head_b, float* __restrict__ out) {
  const int b = blockIdx.x, t = threadIdx.x;
  __shared__ float m[512];
  const int a0 = a_of[b * 2], a1 = a_of[b * 2 + 1];
  const float g0 = ws_gw[b * 2], g1 = ws_gw[b * 2 + 1];
  for (int d = t; d < 512; d += 256)
    m[d] = g0 * O[(size_t)a0 * 512 + d] + g1 * O[(size_t)a1 * 512 + d];
  __syncthreads();
  if (t < 160) {
    const int c = t >> 4, ch = t & 15;
    float p = 0.f;
#pragma unroll
    for (int i = 0; i < 32; i++) {
      const int d = i * 16 + ch;
      p += m[d] * head_W[d * 10 + c];
    }
#pragma unroll
    for (int o = 8; o > 0; o >>= 1) p += __shfl_down(p, o, 16);
    if (ch == 0) out[b * 10 + c] = p + head_b[c];
  }
}

// ------------------------------ launch --------------------------------------
extern "C" void kernel_launch(void* const* d_in, const int* in_sizes, int n_in,
                              void* d_out, int out_size, void* d_ws, size_t ws_size,
                              hipStream_t stream) {
  const int* ipc_idx = (const int*)d_in[0];
  const int* role_idx = (const int*)d_in[1];
  const float* bib = (const float*)d_in[2];
  const int* maskp = (const int*)d_in[3];
  const float* ipc_emb = (const float*)d_in[5];
  const float* role_emb = (const float*)d_in[6];
  const float* Wq = (const float*)d_in[7];
  const float* bq = (const float*)d_in[8];
  const float* Wk = (const float*)d_in[9];
  const float* bk = (const float*)d_in[10];
  const float* Wv = (const float*)d_in[11];
  const float* bv = (const float*)d_in[12];
  const float* gc = (const float*)d_in[13];
  const float* ln_g = (const float*)d_in[14];
  const float* ln_b = (const float*)d_in[15];
  const float* gate_W = (const float*)d_in[16];
  const float* gate_b = (const float*)d_in[17];
  const float* exp_b = (const float*)d_in[18];
  const float* W1 = (const float*)d_in[19];
  const float* b1 = (const float*)d_in[20];
  const float* W2 = (const float*)d_in[21];
  const float* b2 = (const float*)d_in[22];
  const float* W3 = (const float*)d_in[23];
  const float* b3 = (const float*)d_in[24];
  const float* head_W = (const float*)d_in[25];
  const float* head_b = (const float*)d_in[26];

  char* ws = (char*)d_ws;
  size_t off = 0;
  auto alloc = [&](size_t bytes) -> char* {
    char* p = ws + off;
    off += (bytes + 255) & ~(size_t)255;
    return p;
  };
  float* kq_qbk = (float*)alloc(257 * 4);
  float* tab = (float*)alloc(50016 * 4);
  float* xbar_g = (float*)alloc((size_t)2048 * 256 * 4);
  int* ws_idx = (int*)alloc(4096 * 4);
  float* ws_gw = (float*)alloc(4096 * 4);
  int* list_tok = (int*)alloc(4096 * 4);
  int* a_of = (int*)alloc(4096 * 4);
  int* offs = (int*)alloc(9 * 4);
  bf16_t* W1t = (bf16_t*)alloc((size_t)8 * 1024 * 512 * 2);
  bf16_t* W2t = (bf16_t*)alloc((size_t)8 * 1024 * 1024 * 2);
  bf16_t* W3t = (bf16_t*)alloc((size_t)8 * 512 * 1024 * 2);
  bf16_t* Xc = (bf16_t*)alloc((size_t)4224 * 512 * 2);   // +pad rows
  bf16_t* H1c = (bf16_t*)alloc((size_t)4224 * 1024 * 2);
  bf16_t* H2c = (bf16_t*)alloc((size_t)4224 * 1024 * 2);
  float* Oc = (float*)alloc((size_t)4224 * 512 * 4);
  (void)in_sizes; (void)n_in; (void)out_size; (void)ws_size;

  float* out_logits = (float*)d_out;          // [2048*10]
  float* out_idx = (float*)d_out + 20480;     // [2048*2] as float

  prep_kq<<<32, 256, 0, stream>>>(Wq, bq, Wk, bk, gc, kq_qbk);
  transpose_all<<<dim3(16, 16, 24), 256, 0, stream>>>(W1, W2, W3, W1t, W2t, W3t);
  score_tab_kernel<<<391, 256, 0, stream>>>(ipc_emb, role_emb, kq_qbk, tab);
  xbar_kernel<<<2048, 256, 0, stream>>>(ipc_idx, role_idx, maskp, ipc_emb, role_emb,
                                        tab, xbar_g);
  pool_kernel<<<256, 256, 0, stream>>>(xbar_g, Wv, bv, ln_g, ln_b, gate_W, gate_b,
                                       exp_b, out_idx, ws_idx, ws_gw);
  pack_kernel<<<1, 256, 0, stream>>>(ws_idx, list_tok, a_of, offs);
  gather_bib<<<4096, 64, 0, stream>>>(bib, list_tok, Xc);
  expert_gemm<true, bf16_t><<<dim3(16, 32, 8), 256, 0, stream>>>(Xc, W1t, b1, H1c, offs, 512, 1024);
  expert_gemm<true, bf16_t><<<dim3(16, 32, 8), 256, 0, stream>>>(H1c, W2t, b2, H2c, offs, 1024, 1024);
  expert_gemm<false, float><<<dim3(8, 32, 8), 256, 0, stream>>>(H2c, W3t, b3, Oc, offs, 1024, 512);
  head_kernel<<<2048, 256, 0, stream>>>(Oc, a_of, ws_gw, head_W, head_b, out_logits);
}

// Round 6
// 384.424 us; speedup vs baseline: 1.1608x; 1.1608x over previous
//
#include <hip/hip_runtime.h>
#include <hip/hip_bf16.h>
#include <math.h>

// ---------------------------------------------------------------------------
// PatentCitationMoEModule — MI355X implementation, round 6
//  Round 5 (LDS-free/barrier-free FT GEMM) with the one-line fix:
//  B-frag base pointer used frag-base*64 elements instead of *512
//  (layout is ((nt*nk+kt)*64 + lane)*8 ELEMENTS). n0>0 tiles read wrong
//  weights -> absmax 7.5. Now: (n0>>4)*nk*512 + lane*8.
// ---------------------------------------------------------------------------

#define LN_EPS 1e-5f

typedef __bf16 bf16_t;
typedef __bf16 bf16x8 __attribute__((ext_vector_type(8)));
typedef float f32x4 __attribute__((ext_vector_type(4)));

// --------------------------- prep: kq vector -------------------------------
__global__ __launch_bounds__(256)
void prep_kq(const float* __restrict__ Wq, const float* __restrict__ bq,
             const float* __restrict__ Wk, const float* __restrict__ bk,
             const float* __restrict__ gc, float* __restrict__ kq_out) {
  __shared__ float q[256];
  __shared__ float red[4];
  const int t = threadIdx.x, bi = blockIdx.x;
  float s = bq[t];
  for (int d = 0; d < 256; d++) s += gc[d] * Wq[d * 256 + t];
  q[t] = s;
  __syncthreads();
  const int rl = t >> 5, sl = t & 31;
  const int r = bi * 8 + rl;
  float p = 0.f;
#pragma unroll
  for (int i = 0; i < 8; i++) { const int d = sl + 32 * i; p += Wk[r * 256 + d] * q[d]; }
#pragma unroll
  for (int o = 16; o > 0; o >>= 1) p += __shfl_down(p, o, 32);
  if (sl == 0) kq_out[r] = p;
  if (bi == 0) {
    float z = q[t] * bk[t];
    const int lane = t & 63, wave = t >> 6;
#pragma unroll
    for (int o = 32; o > 0; o >>= 1) z += __shfl_down(z, o);
    if (lane == 0) red[wave] = z;
    __syncthreads();
    if (t == 0) kq_out[256] = red[0] + red[1] + red[2] + red[3];
  }
}

// ---------- weight transpose fp32[E][K][N] -> bf16 FT-B layout --------------
// FT-B: frag (nt,kt) = 64 lanes x 8 bf16; lane holds n=nt*16+(lane&15),
// k = kt*32+(lane>>4)*8 .. +7.  Flat elem offset: ((nt*(K/32)+kt)*64+lane)*8.
__global__ __launch_bounds__(256)
void transpose_ft(const float* __restrict__ W1, const float* __restrict__ W2,
                  const float* __restrict__ W3, bf16_t* __restrict__ B1,
                  bf16_t* __restrict__ B2, bf16_t* __restrict__ B3) {
  __shared__ float tile[64][65];
  const int z = blockIdx.z;
  const float* W; bf16_t* Bft; int K, N, e;
  if (z < 8)       { W = W1; Bft = B1; K = 512;  N = 1024; e = z; }
  else if (z < 16) { W = W2; Bft = B2; K = 1024; N = 1024; e = z - 8; }
  else             { W = W3; Bft = B3; K = 1024; N = 512;  e = z - 16; }
  const int n0 = blockIdx.x * 64, k0 = blockIdx.y * 64;
  if (n0 >= N || k0 >= K) return;
  const float* Wp = W + (size_t)e * K * N;
  bf16_t* Bp = Bft + (size_t)e * N * K;
  const int tq = threadIdx.x & 15, th = threadIdx.x >> 4;  // 16 x 16
#pragma unroll
  for (int i = 0; i < 4; i++) {
    const int row = th + 16 * i;  // k-dim
    *(float4*)&tile[row][tq * 4] = *(const float4*)(Wp + (size_t)(k0 + row) * N + n0 + tq * 4);
  }
  __syncthreads();
  const int lane = threadIdx.x & 63, sub = threadIdx.x >> 6;
  const int nk = K >> 5;
#pragma unroll
  for (int it = 0; it < 2; it++) {
    const int fid = sub + it * 4;            // 8 frag-tiles in a 64x64 tile
    const int ntl = fid & 3, ktl = fid >> 2;
    const int n_l = ntl * 16 + (lane & 15);
    const int k_l = ktl * 32 + (lane >> 4) * 8;
    bf16x8 o;
#pragma unroll
    for (int j = 0; j < 8; j++) o[j] = (bf16_t)tile[k_l + j][n_l];
    const size_t idx = ((((size_t)(n0 >> 4) + ntl) * nk + (k0 >> 5) + ktl) * 64 + lane) * 8;
    *(bf16x8*)(Bp + idx) = o;
  }
}

// ---------------- dense score table: tab[v] = emb[v] . kq -------------------
__global__ __launch_bounds__(256)
void score_tab_kernel(const float* __restrict__ ipc_emb,
                      const float* __restrict__ role_emb,
                      const float* __restrict__ kq_qbk, float* __restrict__ tab) {
  const int wave = threadIdx.x >> 6, lane = threadIdx.x & 63;
  const float4 kq = *(const float4*)(kq_qbk + lane * 4);
  const int base = (blockIdx.x * 4 + wave) * 32;
  for (int i = 0; i < 32; i++) {
    const int r = base + i;
    if (r >= 50016) return;
    const float* src = (r < 50000) ? (ipc_emb + (size_t)r * 256)
                                   : (role_emb + (size_t)(r - 50000) * 256);
    const float4 v = *(const float4*)(src + lane * 4);
    float p = v.x * kq.x + v.y * kq.y + v.z * kq.z + v.w * kq.w;
#pragma unroll
    for (int o = 32; o > 0; o >>= 1) p += __shfl_down(p, o);
    if (lane == 0) tab[r] = (r < 50000) ? p : (p + kq_qbk[256]);
  }
}

// -------------------- xbar: softmax + single-pass gather --------------------
__global__ __launch_bounds__(256)
void xbar_kernel(const int* __restrict__ ipc_idx, const int* __restrict__ role_idx,
                 const int* __restrict__ maskp,
                 const float* __restrict__ ipc_emb, const float* __restrict__ role_emb,
                 const float* __restrict__ tab, float* __restrict__ xbar_g) {
  const int b = blockIdx.x;
  __shared__ float attn_s[64];
  __shared__ __align__(16) float part[4][256];
  const int t = threadIdx.x, wave = t >> 6, lane = t & 63;
  const int d0 = lane * 4;
  if (wave == 0) {
    const int ii = ipc_idx[b * 64 + lane], ri = role_idx[b * 64 + lane];
    float s = tab[ii] + tab[50000 + ri];
    s = (maskp[b * 64 + lane] == 0) ? -1e9f : s;
    float m = s;
#pragma unroll
    for (int o = 32; o > 0; o >>= 1) m = fmaxf(m, __shfl_xor(m, o));
    const float ev = expf(s - m);
    float sum = ev;
#pragma unroll
    for (int o = 32; o > 0; o >>= 1) sum += __shfl_xor(sum, o);
    attn_s[lane] = ev / sum;
  }
  __syncthreads();
  float p0 = 0.f, p1 = 0.f, p2 = 0.f, p3 = 0.f;
  for (int l = wave; l < 64; l += 4) {
    const float a = attn_s[l];
    const int ii = ipc_idx[b * 64 + l], ri = role_idx[b * 64 + l];
    const float4 xe = *(const float4*)(ipc_emb + (size_t)ii * 256 + d0);
    const float4 re = *(const float4*)(role_emb + (size_t)ri * 256 + d0);
    p0 += a * (xe.x + re.x); p1 += a * (xe.y + re.y);
    p2 += a * (xe.z + re.z); p3 += a * (xe.w + re.w);
  }
  *(float4*)&part[wave][d0] = make_float4(p0, p1, p2, p3);
  __syncthreads();
  xbar_g[(size_t)b * 256 + t] = part[0][t] + part[1][t] + part[2][t] + part[3][t];
}

// ------------- pool: pooled = xbar@Wv + bv, LN, gate, top2 ------------------
__global__ __launch_bounds__(256)
void pool_kernel(const float* __restrict__ xbar_g, const float* __restrict__ Wv,
                 const float* __restrict__ bvec,
                 const float* __restrict__ ln_g, const float* __restrict__ ln_b,
                 const float* __restrict__ gate_W, const float* __restrict__ gate_b,
                 const float* __restrict__ expert_biases,
                 float* __restrict__ out_idx_f, int* __restrict__ ws_idx,
                 float* __restrict__ ws_gw) {
  const int rb = blockIdx.x * 8;
  __shared__ __align__(16) float xs[8][256];
  __shared__ __align__(16) float ps[8][260];
  const int t = threadIdx.x, wave = t >> 6, lane = t & 63;
  for (int i = t; i < 512; i += 256)
    ((float4*)xs)[i] = ((const float4*)(xbar_g + (size_t)rb * 256))[i];
  __syncthreads();
  const float* x0 = xs[wave * 2];
  const float* x1 = xs[wave * 2 + 1];
  f32x4 acc0 = {0.f, 0.f, 0.f, 0.f}, acc1 = {0.f, 0.f, 0.f, 0.f};
  for (int d = 0; d < 256; d += 4) {
    const float4 xa = *(const float4*)(x0 + d);
    const float4 xb = *(const float4*)(x1 + d);
#pragma unroll
    for (int j = 0; j < 4; j++) {
      const float4 wv = *(const float4*)(Wv + (size_t)(d + j) * 256 + lane * 4);
      const float aj = (&xa.x)[j], bj = (&xb.x)[j];
      acc0.x += aj * wv.x; acc0.y += aj * wv.y; acc0.z += aj * wv.z; acc0.w += aj * wv.w;
      acc1.x += bj * wv.x; acc1.y += bj * wv.y; acc1.z += bj * wv.z; acc1.w += bj * wv.w;
    }
  }
  const float4 bvv = *(const float4*)(bvec + lane * 4);
  acc0.x += bvv.x; acc0.y += bvv.y; acc0.z += bvv.z; acc0.w += bvv.w;
  acc1.x += bvv.x; acc1.y += bvv.y; acc1.z += bvv.z; acc1.w += bvv.w;
  *(f32x4*)&ps[wave * 2][lane * 4] = acc0;
  *(f32x4*)&ps[wave * 2 + 1][lane * 4] = acc1;
  __syncthreads();
  const float4 lg = *(const float4*)(ln_g + lane * 4);
  const float4 lb = *(const float4*)(ln_b + lane * 4);
#pragma unroll
  for (int rr = 0; rr < 2; rr++) {
    const int r = wave * 2 + rr;
    const float4 v = *(const float4*)&ps[r][lane * 4];
    float s1 = v.x + v.y + v.z + v.w;
#pragma unroll
    for (int o = 32; o > 0; o >>= 1) s1 += __shfl_xor(s1, o);
    const float mu = s1 * (1.f / 256.f);
    const float4 df = make_float4(v.x - mu, v.y - mu, v.z - mu, v.w - mu);
    float s2 = df.x * df.x + df.y * df.y + df.z * df.z + df.w * df.w;
#pragma unroll
    for (int o = 32; o > 0; o >>= 1) s2 += __shfl_xor(s2, o);
    const float inv = 1.f / sqrtf(s2 * (1.f / 256.f) + LN_EPS);
    f32x4 rv;
    rv[0] = df.x * inv * lg.x + lb.x; rv[1] = df.y * inv * lg.y + lb.y;
    rv[2] = df.z * inv * lg.z + lb.z; rv[3] = df.w * inv * lg.w + lb.w;
    f32x4 pa = {0.f, 0.f, 0.f, 0.f}, pb = {0.f, 0.f, 0.f, 0.f};
#pragma unroll
    for (int k = 0; k < 4; k++) {
      const int d = lane * 4 + k;
      const f32x4 g0 = *(const f32x4*)(gate_W + d * 8);
      const f32x4 g1 = *(const f32x4*)(gate_W + d * 8 + 4);
      pa += rv[k] * g0;
      pb += rv[k] * g1;
    }
#pragma unroll
    for (int o = 32; o > 0; o >>= 1) {
      pa[0] += __shfl_down(pa[0], o); pa[1] += __shfl_down(pa[1], o);
      pa[2] += __shfl_down(pa[2], o); pa[3] += __shfl_down(pa[3], o);
      pb[0] += __shfl_down(pb[0], o); pb[1] += __shfl_down(pb[1], o);
      pb[2] += __shfl_down(pb[2], o); pb[3] += __shfl_down(pb[3], o);
    }
    if (lane == 0) {
      float aff[8];
#pragma unroll
      for (int j = 0; j < 4; j++) { aff[j] = pa[j] + gate_b[j]; aff[4 + j] = pb[j] + gate_b[4 + j]; }
      float b0 = -1e30f; int i0 = 0;
#pragma unroll
      for (int j = 0; j < 8; j++) {
        const float s = aff[j] + expert_biases[j];
        if (s > b0) { b0 = s; i0 = j; }
      }
      float b1v = -1e30f; int i1 = 0;
#pragma unroll
      for (int j = 0; j < 8; j++) {
        const float s = aff[j] + expert_biases[j];
        if (j != i0 && s > b1v) { b1v = s; i1 = j; }
      }
      const float a0 = aff[i0], a1 = aff[i1];
      const float m = fmaxf(a0, a1);
      const float e0 = expf(a0 - m), e1 = expf(a1 - m);
      const float invs = 1.f / (e0 + e1);
      const int bg = rb + r;
      ws_idx[bg * 2] = i0; ws_idx[bg * 2 + 1] = i1;
      ws_gw[bg * 2] = e0 * invs; ws_gw[bg * 2 + 1] = e1 * invs;
      out_idx_f[bg * 2] = (float)i0; out_idx_f[bg * 2 + 1] = (float)i1;
    }
  }
}

// ------------------------ pack (64-aligned segments) ------------------------
__global__ __launch_bounds__(256)
void pack_kernel(const int* __restrict__ ws_idx, int* __restrict__ list_token,
                 int* __restrict__ a_of, int* __restrict__ offsets_g) {
  __shared__ int cnt[8]; __shared__ int off[9]; __shared__ int fill[8];
  const int t = threadIdx.x;
  if (t < 8) cnt[t] = 0;
  __syncthreads();
  for (int a = t; a < 4096; a += 256) atomicAdd(&cnt[ws_idx[a]], 1);
  __syncthreads();
  if (t == 0) {
    off[0] = 0;
    for (int e = 0; e < 8; e++) off[e + 1] = off[e] + ((cnt[e] + 63) & ~63);
  }
  __syncthreads();
  if (t < 8) fill[t] = off[t];
  if (t < 9) offsets_g[t] = off[t];
  for (int a = t; a < 4608; a += 256) list_token[a] = 0;  // pad rows -> token 0
  __syncthreads();
  for (int a = t; a < 4096; a += 256) {
    const int e = ws_idx[a];
    const int pos = atomicAdd(&fill[e], 1);
    list_token[pos] = a >> 1;
    a_of[a] = pos;
  }
}

// --------------------------- gather bib -> bf16 ----------------------------
__global__ __launch_bounds__(64)
void gather_bib(const float* __restrict__ bib, const int* __restrict__ list_token,
                bf16_t* __restrict__ Xc) {
  const int a = blockIdx.x;
  const int tok = list_token[a];
  const int t = threadIdx.x;
  const float4 v1 = *(const float4*)(bib + (size_t)tok * 512 + t * 8);
  const float4 v2 = *(const float4*)(bib + (size_t)tok * 512 + t * 8 + 4);
  bf16x8 o;
  o[0] = (bf16_t)v1.x; o[1] = (bf16_t)v1.y; o[2] = (bf16_t)v1.z; o[3] = (bf16_t)v1.w;
  o[4] = (bf16_t)v2.x; o[5] = (bf16_t)v2.y; o[6] = (bf16_t)v2.z; o[7] = (bf16_t)v2.w;
  *(bf16x8*)(Xc + (size_t)a * 512 + t * 8) = o;
}

// ---------------- expert GEMM: LDS-free, barrier-free, FT-B -----------------
// C[rows,NT] = A[rows,K] @ B_e; A row-major (L2-hot), Bft in FT layout.
// Block = 4 waves stacked along M (128 rows); wave = independent 32x64 tile
// (acc 2x4 of 16x16).  K fully unrolled, 2-deep register prefetch, no LDS,
// no __syncthreads -> compiler interleaves MFMA with vmcnt(N>0) loads.
template <int K, int NT, bool RELU, typename OUT_T>
__global__ __launch_bounds__(256)
void expert_gemm_ft(const bf16_t* __restrict__ A, const bf16_t* __restrict__ Bft,
                    const float* __restrict__ bias, OUT_T* __restrict__ C,
                    const int* __restrict__ offsets) {
  constexpr int nk = K / 32;
  const int e = blockIdx.z;
  const int seg_hi = offsets[e + 1];
  const int blk_row = offsets[e] + blockIdx.y * 128;
  if (blk_row >= seg_hi) return;
  const int wave = threadIdx.x >> 6, lane = threadIdx.x & 63;
  const int row0 = blk_row + wave * 32;
  if (row0 >= seg_hi) return;  // wave-uniform
  const int n0 = blockIdx.x * 64;
  // A-frag source: lane holds row=(lane&15), k-window=(lane>>4)*8
  const bf16_t* Ap = A + (size_t)(row0 + (lane & 15)) * K + ((lane >> 4) * 8);
  // B-frag source (FT): frag(nt,kt) at elem (nt*nk+kt)*512 + lane*8
  const bf16_t* Bp = Bft + (size_t)e * NT * K + ((size_t)(n0 >> 4) * nk * 512 + lane * 8);
  f32x4 acc[2][4];
#pragma unroll
  for (int i = 0; i < 2; i++)
#pragma unroll
    for (int j = 0; j < 4; j++) acc[i][j] = (f32x4){0.f, 0.f, 0.f, 0.f};
  bf16x8 aX[2][2], bX[2][4];
#pragma unroll
  for (int mi = 0; mi < 2; mi++) aX[0][mi] = *(const bf16x8*)(Ap + mi * 16 * K);
#pragma unroll
  for (int ni = 0; ni < 4; ni++) bX[0][ni] = *(const bf16x8*)(Bp + (size_t)ni * nk * 512);
#pragma unroll
  for (int kt = 0; kt < nk; kt++) {
    const int cur = kt & 1, nxt = cur ^ 1;
    if (kt + 1 < nk) {
#pragma unroll
      for (int mi = 0; mi < 2; mi++)
        aX[nxt][mi] = *(const bf16x8*)(Ap + mi * 16 * K + (kt + 1) * 32);
#pragma unroll
      for (int ni = 0; ni < 4; ni++)
        bX[nxt][ni] = *(const bf16x8*)(Bp + ((size_t)ni * nk + kt + 1) * 512);
    }
#pragma unroll
    for (int mi = 0; mi < 2; mi++)
#pragma unroll
      for (int ni = 0; ni < 4; ni++)
        acc[mi][ni] = __builtin_amdgcn_mfma_f32_16x16x32_bf16(aX[cur][mi], bX[cur][ni], acc[mi][ni], 0, 0, 0);
  }
  // epilogue: C/D layout row=(lane>>4)*4+r, col=lane&15 [m89/m91 verified].
  // Padded segments => all rows valid, no guards.
  const int fr = lane & 15, q = lane >> 4;
#pragma unroll
  for (int ni = 0; ni < 4; ni++) {
    const int col = n0 + ni * 16 + fr;
    const float bv = bias[e * NT + col];
#pragma unroll
    for (int mi = 0; mi < 2; mi++) {
#pragma unroll
      for (int r = 0; r < 4; r++) {
        const int row = row0 + mi * 16 + q * 4 + r;
        float v = acc[mi][ni][r] + bv;
        if (RELU) v = fmaxf(v, 0.f);
        C[(size_t)row * NT + col] = (OUT_T)v;
      }
    }
  }
}

// ------------------------------ head ---------------------------------------
__global__ __launch_bounds__(256)
void head_kernel(const float* __restrict__ O, const int* __restrict__ a_of,
                 const float* __restrict__ ws_gw, const float* __restrict__ head_W,
                 const float* __restrict__ head_b, float* __restrict__ out) {
  const int b = blockIdx.x, t = threadIdx.x;
  __shared__ float m[512];
  const int a0 = a_of[b * 2], a1 = a_of[b * 2 + 1];
  const float g0 = ws_gw[b * 2], g1 = ws_gw[b * 2 + 1];
  for (int d = t; d < 512; d += 256)
    m[d] = g0 * O[(size_t)a0 * 512 + d] + g1 * O[(size_t)a1 * 512 + d];
  __syncthreads();
  if (t < 160) {
    const int c = t >> 4, ch = t & 15;
    float p = 0.f;
#pragma unroll
    for (int i = 0; i < 32; i++) {
      const int d = i * 16 + ch;
      p += m[d] * head_W[d * 10 + c];
    }
#pragma unroll
    for (int o = 8; o > 0; o >>= 1) p += __shfl_down(p, o, 16);
    if (ch == 0) out[b * 10 + c] = p + head_b[c];
  }
}

// ------------------------------ launch --------------------------------------
extern "C" void kernel_launch(void* const* d_in, const int* in_sizes, int n_in,
                              void* d_out, int out_size, void* d_ws, size_t ws_size,
                              hipStream_t stream) {
  const int* ipc_idx = (const int*)d_in[0];
  const int* role_idx = (const int*)d_in[1];
  const float* bib = (const float*)d_in[2];
  const int* maskp = (const int*)d_in[3];
  const float* ipc_emb = (const float*)d_in[5];
  const float* role_emb = (const float*)d_in[6];
  const float* Wq = (const float*)d_in[7];
  const float* bq = (const float*)d_in[8];
  const float* Wk = (const float*)d_in[9];
  const float* bk = (const float*)d_in[10];
  const float* Wv = (const float*)d_in[11];
  const float* bv = (const float*)d_in[12];
  const float* gc = (const float*)d_in[13];
  const float* ln_g = (const float*)d_in[14];
  const float* ln_b = (const float*)d_in[15];
  const float* gate_W = (const float*)d_in[16];
  const float* gate_b = (const float*)d_in[17];
  const float* exp_b = (const float*)d_in[18];
  const float* W1 = (const float*)d_in[19];
  const float* b1 = (const float*)d_in[20];
  const float* W2 = (const float*)d_in[21];
  const float* b2 = (const float*)d_in[22];
  const float* W3 = (const float*)d_in[23];
  const float* b3 = (const float*)d_in[24];
  const float* head_W = (const float*)d_in[25];
  const float* head_b = (const float*)d_in[26];

  char* ws = (char*)d_ws;
  size_t off = 0;
  auto alloc = [&](size_t bytes) -> char* {
    char* p = ws + off;
    off += (bytes + 255) & ~(size_t)255;
    return p;
  };
  float* kq_qbk = (float*)alloc(257 * 4);
  float* tab = (float*)alloc(50016 * 4);
  float* xbar_g = (float*)alloc((size_t)2048 * 256 * 4);
  int* ws_idx = (int*)alloc(4096 * 4);
  float* ws_gw = (float*)alloc(4096 * 4);
  int* list_tok = (int*)alloc(4608 * 4);
  int* a_of = (int*)alloc(4096 * 4);
  int* offs = (int*)alloc(9 * 4);
  bf16_t* W1t = (bf16_t*)alloc((size_t)8 * 1024 * 512 * 2);
  bf16_t* W2t = (bf16_t*)alloc((size_t)8 * 1024 * 1024 * 2);
  bf16_t* W3t = (bf16_t*)alloc((size_t)8 * 512 * 1024 * 2);
  bf16_t* Xc = (bf16_t*)alloc((size_t)4608 * 512 * 2);
  bf16_t* H1c = (bf16_t*)alloc((size_t)4608 * 1024 * 2);
  bf16_t* H2c = (bf16_t*)alloc((size_t)4608 * 1024 * 2);
  float* Oc = (float*)alloc((size_t)4608 * 512 * 4);
  (void)in_sizes; (void)n_in; (void)out_size; (void)ws_size;

  float* out_logits = (float*)d_out;          // [2048*10]
  float* out_idx = (float*)d_out + 20480;     // [2048*2] as float

  prep_kq<<<32, 256, 0, stream>>>(Wq, bq, Wk, bk, gc, kq_qbk);
  transpose_ft<<<dim3(16, 16, 24), 256, 0, stream>>>(W1, W2, W3, W1t, W2t, W3t);
  score_tab_kernel<<<391, 256, 0, stream>>>(ipc_emb, role_emb, kq_qbk, tab);
  xbar_kernel<<<2048, 256, 0, stream>>>(ipc_idx, role_idx, maskp, ipc_emb, role_emb,
                                        tab, xbar_g);
  pool_kernel<<<256, 256, 0, stream>>>(xbar_g, Wv, bv, ln_g, ln_b, gate_W, gate_b,
                                       exp_b, out_idx, ws_idx, ws_gw);
  pack_kernel<<<1, 256, 0, stream>>>(ws_idx, list_tok, a_of, offs);
  gather_bib<<<4608, 64, 0, stream>>>(bib, list_tok, Xc);
  expert_gemm_ft<512, 1024, true, bf16_t><<<dim3(16, 36, 8), 256, 0, stream>>>(Xc, W1t, b1, H1c, offs);
  expert_gemm_ft<1024, 1024, true, bf16_t><<<dim3(16, 36, 8), 256, 0, stream>>>(H1c, W2t, b2, H2c, offs);
  expert_gemm_ft<1024, 512, false, float><<<dim3(8, 36, 8), 256, 0, stream>>>(H2c, W3t, b3, Oc, offs);
  head_kernel<<<2048, 256, 0, stream>>>(Oc, a_of, ws_gw, head_W, head_b, out_logits);
}

// Round 7
// 379.672 us; speedup vs baseline: 1.1753x; 1.0125x over previous
//
#include <hip/hip_runtime.h>
#include <hip/hip_bf16.h>
#include <math.h>

// ---------------------------------------------------------------------------
// PatentCitationMoEModule — MI355X implementation, round 7
//  Round 6 (384 us) plus:
//   - xbar: skip rows with attn == 0.0f (exactly matches reference; ~half of
//     rows are masked) -> halves the embedding gather traffic.
//   - gather_bib fused into GEMM-1 (A read fp32 from bib via list_token with
//     in-register bf16 convert; identical rounding).
//   - prep_kq merged into the transpose dispatch (z==24 slice).
//  Fixed harness overhead (ws poison fill ~40us + d_in restore) is untouchable.
// ---------------------------------------------------------------------------

#define LN_EPS 1e-5f

typedef __bf16 bf16_t;
typedef __bf16 bf16x8 __attribute__((ext_vector_type(8)));
typedef float f32x4 __attribute__((ext_vector_type(4)));

struct f4x2 { float4 a, b; };
__device__ __forceinline__ f4x2 ldA8(const float* p) {
  f4x2 v; v.a = *(const float4*)p; v.b = *(const float4*)(p + 4); return v;
}
__device__ __forceinline__ bf16x8 cvt8(const f4x2& v) {
  bf16x8 o;
  o[0] = (bf16_t)v.a.x; o[1] = (bf16_t)v.a.y; o[2] = (bf16_t)v.a.z; o[3] = (bf16_t)v.a.w;
  o[4] = (bf16_t)v.b.x; o[5] = (bf16_t)v.b.y; o[6] = (bf16_t)v.b.z; o[7] = (bf16_t)v.b.w;
  return o;
}

// -------- merged: weight transpose->FT layout (z<24) + prep_kq (z==24) -----
// FT-B: frag (nt,kt) = 64 lanes x 8 bf16; lane holds n=nt*16+(lane&15),
// k = kt*32+(lane>>4)*8 .. +7.  Flat elem offset: ((nt*(K/32)+kt)*64+lane)*8.
__global__ __launch_bounds__(256)
void transpose_prep(const float* __restrict__ W1, const float* __restrict__ W2,
                    const float* __restrict__ W3, bf16_t* __restrict__ B1,
                    bf16_t* __restrict__ B2, bf16_t* __restrict__ B3,
                    const float* __restrict__ Wq, const float* __restrict__ bq,
                    const float* __restrict__ Wk, const float* __restrict__ bk,
                    const float* __restrict__ gc, float* __restrict__ kq_out) {
  __shared__ float tile[64][65];
  const int z = blockIdx.z;
  if (z == 24) {
    // ---- prep_kq path: 32 active blocks (y<2), bi = y*16+x ----
    if (blockIdx.y >= 2) return;
    float* q = &tile[0][0];        // alias LDS: q[0..255], red[256..259]
    float* red = &tile[0][0] + 256;
    const int t = threadIdx.x, bi = blockIdx.y * 16 + blockIdx.x;
    float s = bq[t];
    for (int d = 0; d < 256; d++) s += gc[d] * Wq[d * 256 + t];
    q[t] = s;
    __syncthreads();
    const int rl = t >> 5, sl = t & 31;
    const int r = bi * 8 + rl;
    float p = 0.f;
#pragma unroll
    for (int i = 0; i < 8; i++) { const int d = sl + 32 * i; p += Wk[r * 256 + d] * q[d]; }
#pragma unroll
    for (int o = 16; o > 0; o >>= 1) p += __shfl_down(p, o, 32);
    if (sl == 0) kq_out[r] = p;
    if (bi == 0) {
      float z2 = q[t] * bk[t];
      const int lane = t & 63, wave = t >> 6;
#pragma unroll
      for (int o = 32; o > 0; o >>= 1) z2 += __shfl_down(z2, o);
      if (lane == 0) red[wave] = z2;
      __syncthreads();
      if (t == 0) kq_out[256] = red[0] + red[1] + red[2] + red[3];
    }
    return;
  }
  // ---- transpose path ----
  const float* W; bf16_t* Bft; int K, N, e;
  if (z < 8)       { W = W1; Bft = B1; K = 512;  N = 1024; e = z; }
  else if (z < 16) { W = W2; Bft = B2; K = 1024; N = 1024; e = z - 8; }
  else             { W = W3; Bft = B3; K = 1024; N = 512;  e = z - 16; }
  const int n0 = blockIdx.x * 64, k0 = blockIdx.y * 64;
  if (n0 >= N || k0 >= K) return;
  const float* Wp = W + (size_t)e * K * N;
  bf16_t* Bp = Bft + (size_t)e * N * K;
  const int tq = threadIdx.x & 15, th = threadIdx.x >> 4;  // 16 x 16
#pragma unroll
  for (int i = 0; i < 4; i++) {
    const int row = th + 16 * i;  // k-dim
    *(float4*)&tile[row][tq * 4] = *(const float4*)(Wp + (size_t)(k0 + row) * N + n0 + tq * 4);
  }
  __syncthreads();
  const int lane = threadIdx.x & 63, sub = threadIdx.x >> 6;
  const int nk = K >> 5;
#pragma unroll
  for (int it = 0; it < 2; it++) {
    const int fid = sub + it * 4;            // 8 frag-tiles in a 64x64 tile
    const int ntl = fid & 3, ktl = fid >> 2;
    const int n_l = ntl * 16 + (lane & 15);
    const int k_l = ktl * 32 + (lane >> 4) * 8;
    bf16x8 o;
#pragma unroll
    for (int j = 0; j < 8; j++) o[j] = (bf16_t)tile[k_l + j][n_l];
    const size_t idx = ((((size_t)(n0 >> 4) + ntl) * nk + (k0 >> 5) + ktl) * 64 + lane) * 8;
    *(bf16x8*)(Bp + idx) = o;
  }
}

// ---------------- dense score table: tab[v] = emb[v] . kq -------------------
__global__ __launch_bounds__(256)
void score_tab_kernel(const float* __restrict__ ipc_emb,
                      const float* __restrict__ role_emb,
                      const float* __restrict__ kq_qbk, float* __restrict__ tab) {
  const int wave = threadIdx.x >> 6, lane = threadIdx.x & 63;
  const float4 kq = *(const float4*)(kq_qbk + lane * 4);
  const int base = (blockIdx.x * 4 + wave) * 32;
  for (int i = 0; i < 32; i++) {
    const int r = base + i;
    if (r >= 50016) return;
    const float* src = (r < 50000) ? (ipc_emb + (size_t)r * 256)
                                   : (role_emb + (size_t)(r - 50000) * 256);
    const float4 v = *(const float4*)(src + lane * 4);
    float p = v.x * kq.x + v.y * kq.y + v.z * kq.z + v.w * kq.w;
#pragma unroll
    for (int o = 32; o > 0; o >>= 1) p += __shfl_down(p, o);
    if (lane == 0) tab[r] = (r < 50000) ? p : (p + kq_qbk[256]);
  }
}

// -------------------- xbar: softmax + masked-skip gather --------------------
__global__ __launch_bounds__(256)
void xbar_kernel(const int* __restrict__ ipc_idx, const int* __restrict__ role_idx,
                 const int* __restrict__ maskp,
                 const float* __restrict__ ipc_emb, const float* __restrict__ role_emb,
                 const float* __restrict__ tab, float* __restrict__ xbar_g) {
  const int b = blockIdx.x;
  __shared__ float attn_s[64];
  __shared__ __align__(16) float part[4][256];
  const int t = threadIdx.x, wave = t >> 6, lane = t & 63;
  const int d0 = lane * 4;
  if (wave == 0) {
    const int ii = ipc_idx[b * 64 + lane], ri = role_idx[b * 64 + lane];
    float s = tab[ii] + tab[50000 + ri];
    s = (maskp[b * 64 + lane] == 0) ? -1e9f : s;
    float m = s;
#pragma unroll
    for (int o = 32; o > 0; o >>= 1) m = fmaxf(m, __shfl_xor(m, o));
    const float ev = expf(s - m);
    float sum = ev;
#pragma unroll
    for (int o = 32; o > 0; o >>= 1) sum += __shfl_xor(sum, o);
    attn_s[lane] = ev / sum;
  }
  __syncthreads();
  float p0 = 0.f, p1 = 0.f, p2 = 0.f, p3 = 0.f;
  for (int l = wave; l < 64; l += 4) {
    const float a = attn_s[l];          // wave-uniform
    if (a == 0.f) continue;             // masked row: exp underflow -> exact 0
    const int ii = ipc_idx[b * 64 + l], ri = role_idx[b * 64 + l];
    const float4 xe = *(const float4*)(ipc_emb + (size_t)ii * 256 + d0);
    const float4 re = *(const float4*)(role_emb + (size_t)ri * 256 + d0);
    p0 += a * (xe.x + re.x); p1 += a * (xe.y + re.y);
    p2 += a * (xe.z + re.z); p3 += a * (xe.w + re.w);
  }
  *(float4*)&part[wave][d0] = make_float4(p0, p1, p2, p3);
  __syncthreads();
  xbar_g[(size_t)b * 256 + t] = part[0][t] + part[1][t] + part[2][t] + part[3][t];
}

// ------------- pool: pooled = xbar@Wv + bv, LN, gate, top2 ------------------
__global__ __launch_bounds__(256)
void pool_kernel(const float* __restrict__ xbar_g, const float* __restrict__ Wv,
                 const float* __restrict__ bvec,
                 const float* __restrict__ ln_g, const float* __restrict__ ln_b,
                 const float* __restrict__ gate_W, const float* __restrict__ gate_b,
                 const float* __restrict__ expert_biases,
                 float* __restrict__ out_idx_f, int* __restrict__ ws_idx,
                 float* __restrict__ ws_gw) {
  const int rb = blockIdx.x * 8;
  __shared__ __align__(16) float xs[8][256];
  __shared__ __align__(16) float ps[8][260];
  const int t = threadIdx.x, wave = t >> 6, lane = t & 63;
  for (int i = t; i < 512; i += 256)
    ((float4*)xs)[i] = ((const float4*)(xbar_g + (size_t)rb * 256))[i];
  __syncthreads();
  const float* x0 = xs[wave * 2];
  const float* x1 = xs[wave * 2 + 1];
  f32x4 acc0 = {0.f, 0.f, 0.f, 0.f}, acc1 = {0.f, 0.f, 0.f, 0.f};
  for (int d = 0; d < 256; d += 4) {
    const float4 xa = *(const float4*)(x0 + d);
    const float4 xb = *(const float4*)(x1 + d);
#pragma unroll
    for (int j = 0; j < 4; j++) {
      const float4 wv = *(const float4*)(Wv + (size_t)(d + j) * 256 + lane * 4);
      const float aj = (&xa.x)[j], bj = (&xb.x)[j];
      acc0.x += aj * wv.x; acc0.y += aj * wv.y; acc0.z += aj * wv.z; acc0.w += aj * wv.w;
      acc1.x += bj * wv.x; acc1.y += bj * wv.y; acc1.z += bj * wv.z; acc1.w += bj * wv.w;
    }
  }
  const float4 bvv = *(const float4*)(bvec + lane * 4);
  acc0.x += bvv.x; acc0.y += bvv.y; acc0.z += bvv.z; acc0.w += bvv.w;
  acc1.x += bvv.x; acc1.y += bvv.y; acc1.z += bvv.z; acc1.w += bvv.w;
  *(f32x4*)&ps[wave * 2][lane * 4] = acc0;
  *(f32x4*)&ps[wave * 2 + 1][lane * 4] = acc1;
  __syncthreads();
  const float4 lg = *(const float4*)(ln_g + lane * 4);
  const float4 lb = *(const float4*)(ln_b + lane * 4);
#pragma unroll
  for (int rr = 0; rr < 2; rr++) {
    const int r = wave * 2 + rr;
    const float4 v = *(const float4*)&ps[r][lane * 4];
    float s1 = v.x + v.y + v.z + v.w;
#pragma unroll
    for (int o = 32; o > 0; o >>= 1) s1 += __shfl_xor(s1, o);
    const float mu = s1 * (1.f / 256.f);
    const float4 df = make_float4(v.x - mu, v.y - mu, v.z - mu, v.w - mu);
    float s2 = df.x * df.x + df.y * df.y + df.z * df.z + df.w * df.w;
#pragma unroll
    for (int o = 32; o > 0; o >>= 1) s2 += __shfl_xor(s2, o);
    const float inv = 1.f / sqrtf(s2 * (1.f / 256.f) + LN_EPS);
    f32x4 rv;
    rv[0] = df.x * inv * lg.x + lb.x; rv[1] = df.y * inv * lg.y + lb.y;
    rv[2] = df.z * inv * lg.z + lb.z; rv[3] = df.w * inv * lg.w + lb.w;
    f32x4 pa = {0.f, 0.f, 0.f, 0.f}, pb = {0.f, 0.f, 0.f, 0.f};
#pragma unroll
    for (int k = 0; k < 4; k++) {
      const int d = lane * 4 + k;
      const f32x4 g0 = *(const f32x4*)(gate_W + d * 8);
      const f32x4 g1 = *(const f32x4*)(gate_W + d * 8 + 4);
      pa += rv[k] * g0;
      pb += rv[k] * g1;
    }
#pragma unroll
    for (int o = 32; o > 0; o >>= 1) {
      pa[0] += __shfl_down(pa[0], o); pa[1] += __shfl_down(pa[1], o);
      pa[2] += __shfl_down(pa[2], o); pa[3] += __shfl_down(pa[3], o);
      pb[0] += __shfl_down(pb[0], o); pb[1] += __shfl_down(pb[1], o);
      pb[2] += __shfl_down(pb[2], o); pb[3] += __shfl_down(pb[3], o);
    }
    if (lane == 0) {
      float aff[8];
#pragma unroll
      for (int j = 0; j < 4; j++) { aff[j] = pa[j] + gate_b[j]; aff[4 + j] = pb[j] + gate_b[4 + j]; }
      float b0 = -1e30f; int i0 = 0;
#pragma unroll
      for (int j = 0; j < 8; j++) {
        const float s = aff[j] + expert_biases[j];
        if (s > b0) { b0 = s; i0 = j; }
      }
      float b1v = -1e30f; int i1 = 0;
#pragma unroll
      for (int j = 0; j < 8; j++) {
        const float s = aff[j] + expert_biases[j];
        if (j != i0 && s > b1v) { b1v = s; i1 = j; }
      }
      const float a0 = aff[i0], a1 = aff[i1];
      const float m = fmaxf(a0, a1);
      const float e0 = expf(a0 - m), e1 = expf(a1 - m);
      const float invs = 1.f / (e0 + e1);
      const int bg = rb + r;
      ws_idx[bg * 2] = i0; ws_idx[bg * 2 + 1] = i1;
      ws_gw[bg * 2] = e0 * invs; ws_gw[bg * 2 + 1] = e1 * invs;
      out_idx_f[bg * 2] = (float)i0; out_idx_f[bg * 2 + 1] = (float)i1;
    }
  }
}

// ------------------------ pack (64-aligned segments) ------------------------
__global__ __launch_bounds__(256)
void pack_kernel(const int* __restrict__ ws_idx, int* __restrict__ list_token,
                 int* __restrict__ a_of, int* __restrict__ offsets_g) {
  __shared__ int cnt[8]; __shared__ int off[9]; __shared__ int fill[8];
  const int t = threadIdx.x;
  if (t < 8) cnt[t] = 0;
  __syncthreads();
  for (int a = t; a < 4096; a += 256) atomicAdd(&cnt[ws_idx[a]], 1);
  __syncthreads();
  if (t == 0) {
    off[0] = 0;
    for (int e = 0; e < 8; e++) off[e + 1] = off[e] + ((cnt[e] + 63) & ~63);
  }
  __syncthreads();
  if (t < 8) fill[t] = off[t];
  if (t < 9) offsets_g[t] = off[t];
  for (int a = t; a < 4608; a += 256) list_token[a] = 0;  // pad rows -> token 0
  __syncthreads();
  for (int a = t; a < 4096; a += 256) {
    const int e = ws_idx[a];
    const int pos = atomicAdd(&fill[e], 1);
    list_token[pos] = a >> 1;
    a_of[a] = pos;
  }
}

// --------- GEMM-1: fused bib gather (fp32->bf16 in-register), FT-B ----------
// C[rows,NT] = cvt_bf16(bib[list_token[row]]) @ B1_e ; K=512.
template <int NT, bool RELU>
__global__ __launch_bounds__(256)
void expert_gemm_g1(const float* __restrict__ bib, const int* __restrict__ list_token,
                    const bf16_t* __restrict__ Bft, const float* __restrict__ bias,
                    bf16_t* __restrict__ C, const int* __restrict__ offsets) {
  constexpr int K = 512, nk = K / 32;
  const int e = blockIdx.z;
  const int seg_hi = offsets[e + 1];
  const int blk_row = offsets[e] + blockIdx.y * 128;
  if (blk_row >= seg_hi) return;
  const int wave = threadIdx.x >> 6, lane = threadIdx.x & 63;
  const int row0 = blk_row + wave * 32;
  if (row0 >= seg_hi) return;
  const int n0 = blockIdx.x * 64;
  const int tok0 = list_token[row0 + (lane & 15)];
  const int tok1 = list_token[row0 + 16 + (lane & 15)];
  const float* Ap0 = bib + (size_t)tok0 * 512 + (lane >> 4) * 8;
  const float* Ap1 = bib + (size_t)tok1 * 512 + (lane >> 4) * 8;
  const bf16_t* Bp = Bft + (size_t)e * NT * K + ((size_t)(n0 >> 4) * nk * 512 + lane * 8);
  f32x4 acc[2][4];
#pragma unroll
  for (int i = 0; i < 2; i++)
#pragma unroll
    for (int j = 0; j < 4; j++) acc[i][j] = (f32x4){0.f, 0.f, 0.f, 0.f};
  f4x2 aS[2][2]; bf16x8 bX[2][4];
  aS[0][0] = ldA8(Ap0); aS[0][1] = ldA8(Ap1);
#pragma unroll
  for (int ni = 0; ni < 4; ni++) bX[0][ni] = *(const bf16x8*)(Bp + (size_t)ni * nk * 512);
#pragma unroll
  for (int kt = 0; kt < nk; kt++) {
    const int cur = kt & 1, nxt = cur ^ 1;
    if (kt + 1 < nk) {
      aS[nxt][0] = ldA8(Ap0 + (kt + 1) * 32);
      aS[nxt][1] = ldA8(Ap1 + (kt + 1) * 32);
#pragma unroll
      for (int ni = 0; ni < 4; ni++)
        bX[nxt][ni] = *(const bf16x8*)(Bp + ((size_t)ni * nk + kt + 1) * 512);
    }
    const bf16x8 a0 = cvt8(aS[cur][0]), a1 = cvt8(aS[cur][1]);
#pragma unroll
    for (int ni = 0; ni < 4; ni++) {
      acc[0][ni] = __builtin_amdgcn_mfma_f32_16x16x32_bf16(a0, bX[cur][ni], acc[0][ni], 0, 0, 0);
      acc[1][ni] = __builtin_amdgcn_mfma_f32_16x16x32_bf16(a1, bX[cur][ni], acc[1][ni], 0, 0, 0);
    }
  }
  const int fr = lane & 15, q = lane >> 4;
#pragma unroll
  for (int ni = 0; ni < 4; ni++) {
    const int col = n0 + ni * 16 + fr;
    const float bv = bias[e * NT + col];
#pragma unroll
    for (int mi = 0; mi < 2; mi++) {
#pragma unroll
      for (int r = 0; r < 4; r++) {
        const int row = row0 + mi * 16 + q * 4 + r;
        float v = acc[mi][ni][r] + bv;
        if (RELU) v = fmaxf(v, 0.f);
        C[(size_t)row * NT + col] = (bf16_t)v;
      }
    }
  }
}

// ---------------- expert GEMM: LDS-free, barrier-free, FT-B -----------------
template <int K, int NT, bool RELU, typename OUT_T>
__global__ __launch_bounds__(256)
void expert_gemm_ft(const bf16_t* __restrict__ A, const bf16_t* __restrict__ Bft,
                    const float* __restrict__ bias, OUT_T* __restrict__ C,
                    const int* __restrict__ offsets) {
  constexpr int nk = K / 32;
  const int e = blockIdx.z;
  const int seg_hi = offsets[e + 1];
  const int blk_row = offsets[e] + blockIdx.y * 128;
  if (blk_row >= seg_hi) return;
  const int wave = threadIdx.x >> 6, lane = threadIdx.x & 63;
  const int row0 = blk_row + wave * 32;
  if (row0 >= seg_hi) return;  // wave-uniform
  const int n0 = blockIdx.x * 64;
  const bf16_t* Ap = A + (size_t)(row0 + (lane & 15)) * K + ((lane >> 4) * 8);
  const bf16_t* Bp = Bft + (size_t)e * NT * K + ((size_t)(n0 >> 4) * nk * 512 + lane * 8);
  f32x4 acc[2][4];
#pragma unroll
  for (int i = 0; i < 2; i++)
#pragma unroll
    for (int j = 0; j < 4; j++) acc[i][j] = (f32x4){0.f, 0.f, 0.f, 0.f};
  bf16x8 aX[2][2], bX[2][4];
#pragma unroll
  for (int mi = 0; mi < 2; mi++) aX[0][mi] = *(const bf16x8*)(Ap + mi * 16 * K);
#pragma unroll
  for (int ni = 0; ni < 4; ni++) bX[0][ni] = *(const bf16x8*)(Bp + (size_t)ni * nk * 512);
#pragma unroll
  for (int kt = 0; kt < nk; kt++) {
    const int cur = kt & 1, nxt = cur ^ 1;
    if (kt + 1 < nk) {
#pragma unroll
      for (int mi = 0; mi < 2; mi++)
        aX[nxt][mi] = *(const bf16x8*)(Ap + mi * 16 * K + (kt + 1) * 32);
#pragma unroll
      for (int ni = 0; ni < 4; ni++)
        bX[nxt][ni] = *(const bf16x8*)(Bp + ((size_t)ni * nk + kt + 1) * 512);
    }
#pragma unroll
    for (int mi = 0; mi < 2; mi++)
#pragma unroll
      for (int ni = 0; ni < 4; ni++)
        acc[mi][ni] = __builtin_amdgcn_mfma_f32_16x16x32_bf16(aX[cur][mi], bX[cur][ni], acc[mi][ni], 0, 0, 0);
  }
  const int fr = lane & 15, q = lane >> 4;
#pragma unroll
  for (int ni = 0; ni < 4; ni++) {
    const int col = n0 + ni * 16 + fr;
    const float bv = bias[e * NT + col];
#pragma unroll
    for (int mi = 0; mi < 2; mi++) {
#pragma unroll
      for (int r = 0; r < 4; r++) {
        const int row = row0 + mi * 16 + q * 4 + r;
        float v = acc[mi][ni][r] + bv;
        if (RELU) v = fmaxf(v, 0.f);
        C[(size_t)row * NT + col] = (OUT_T)v;
      }
    }
  }
}

// ------------------------------ head ---------------------------------------
__global__ __launch_bounds__(256)
void head_kernel(const float* __restrict__ O, const int* __restrict__ a_of,
                 const float* __restrict__ ws_gw, const float* __restrict__ head_W,
                 const float* __restrict__ head_b, float* __restrict__ out) {
  const int b = blockIdx.x, t = threadIdx.x;
  __shared__ float m[512];
  const int a0 = a_of[b * 2], a1 = a_of[b * 2 + 1];
  const float g0 = ws_gw[b * 2], g1 = ws_gw[b * 2 + 1];
  for (int d = t; d < 512; d += 256)
    m[d] = g0 * O[(size_t)a0 * 512 + d] + g1 * O[(size_t)a1 * 512 + d];
  __syncthreads();
  if (t < 160) {
    const int c = t >> 4, ch = t & 15;
    float p = 0.f;
#pragma unroll
    for (int i = 0; i < 32; i++) {
      const int d = i * 16 + ch;
      p += m[d] * head_W[d * 10 + c];
    }
#pragma unroll
    for (int o = 8; o > 0; o >>= 1) p += __shfl_down(p, o, 16);
    if (ch == 0) out[b * 10 + c] = p + head_b[c];
  }
}

// ------------------------------ launch --------------------------------------
extern "C" void kernel_launch(void* const* d_in, const int* in_sizes, int n_in,
                              void* d_out, int out_size, void* d_ws, size_t ws_size,
                              hipStream_t stream) {
  const int* ipc_idx = (const int*)d_in[0];
  const int* role_idx = (const int*)d_in[1];
  const float* bib = (const float*)d_in[2];
  const int* maskp = (const int*)d_in[3];
  const float* ipc_emb = (const float*)d_in[5];
  const float* role_emb = (const float*)d_in[6];
  const float* Wq = (const float*)d_in[7];
  const float* bq = (const float*)d_in[8];
  const float* Wk = (const float*)d_in[9];
  const float* bk = (const float*)d_in[10];
  const float* Wv = (const float*)d_in[11];
  const float* bv = (const float*)d_in[12];
  const float* gc = (const float*)d_in[13];
  const float* ln_g = (const float*)d_in[14];
  const float* ln_b = (const float*)d_in[15];
  const float* gate_W = (const float*)d_in[16];
  const float* gate_b = (const float*)d_in[17];
  const float* exp_b = (const float*)d_in[18];
  const float* W1 = (const float*)d_in[19];
  const float* b1 = (const float*)d_in[20];
  const float* W2 = (const float*)d_in[21];
  const float* b2 = (const float*)d_in[22];
  const float* W3 = (const float*)d_in[23];
  const float* b3 = (const float*)d_in[24];
  const float* head_W = (const float*)d_in[25];
  const float* head_b = (const float*)d_in[26];

  char* ws = (char*)d_ws;
  size_t off = 0;
  auto alloc = [&](size_t bytes) -> char* {
    char* p = ws + off;
    off += (bytes + 255) & ~(size_t)255;
    return p;
  };
  float* kq_qbk = (float*)alloc(257 * 4);
  float* tab = (float*)alloc(50016 * 4);
  float* xbar_g = (float*)alloc((size_t)2048 * 256 * 4);
  int* ws_idx = (int*)alloc(4096 * 4);
  float* ws_gw = (float*)alloc(4096 * 4);
  int* list_tok = (int*)alloc(4608 * 4);
  int* a_of = (int*)alloc(4096 * 4);
  int* offs = (int*)alloc(9 * 4);
  bf16_t* W1t = (bf16_t*)alloc((size_t)8 * 1024 * 512 * 2);
  bf16_t* W2t = (bf16_t*)alloc((size_t)8 * 1024 * 1024 * 2);
  bf16_t* W3t = (bf16_t*)alloc((size_t)8 * 512 * 1024 * 2);
  bf16_t* H1c = (bf16_t*)alloc((size_t)4608 * 1024 * 2);
  bf16_t* H2c = (bf16_t*)alloc((size_t)4608 * 1024 * 2);
  float* Oc = (float*)alloc((size_t)4608 * 512 * 4);
  (void)in_sizes; (void)n_in; (void)out_size; (void)ws_size;

  float* out_logits = (float*)d_out;          // [2048*10]
  float* out_idx = (float*)d_out + 20480;     // [2048*2] as float

  transpose_prep<<<dim3(16, 16, 25), 256, 0, stream>>>(W1, W2, W3, W1t, W2t, W3t,
                                                       Wq, bq, Wk, bk, gc, kq_qbk);
  score_tab_kernel<<<391, 256, 0, stream>>>(ipc_emb, role_emb, kq_qbk, tab);
  xbar_kernel<<<2048, 256, 0, stream>>>(ipc_idx, role_idx, maskp, ipc_emb, role_emb,
                                        tab, xbar_g);
  pool_kernel<<<256, 256, 0, stream>>>(xbar_g, Wv, bv, ln_g, ln_b, gate_W, gate_b,
                                       exp_b, out_idx, ws_idx, ws_gw);
  pack_kernel<<<1, 256, 0, stream>>>(ws_idx, list_tok, a_of, offs);
  expert_gemm_g1<1024, true><<<dim3(16, 36, 8), 256, 0, stream>>>(bib, list_tok, W1t, b1, H1c, offs);
  expert_gemm_ft<1024, 1024, true, bf16_t><<<dim3(16, 36, 8), 256, 0, stream>>>(H1c, W2t, b2, H2c, offs);
  expert_gemm_ft<1024, 512, false, float><<<dim3(8, 36, 8), 256, 0, stream>>>(H2c, W3t, b3, Oc, offs);
  head_kernel<<<2048, 256, 0, stream>>>(Oc, a_of, ws_gw, head_W, head_b, out_logits);
}